// Round 12
// baseline (502.111 us; speedup 1.0000x reference)
//
#include <hip/hip_runtime.h>
#include <hip/hip_bf16.h>

using bf16 = __hip_bfloat16;
typedef __attribute__((ext_vector_type(8))) short s8v;     // 8 bf16 in 4 VGPRs
typedef __attribute__((ext_vector_type(4))) float f4v;     // 16x16 mfma accumulator
typedef __attribute__((ext_vector_type(16))) float f16v;   // 32x32 mfma accumulator
typedef __attribute__((ext_vector_type(4))) unsigned int u4v;

#define QSCALE 0.18033688011112042f   /* 0.125 * log2(e) */

// ---------------------------------------------------------------- helpers
__device__ __forceinline__ void gld_lds16(const void* g, void* l) {
  __builtin_amdgcn_global_load_lds(
      (const __attribute__((address_space(1))) void*)g,
      (__attribute__((address_space(3))) void*)l, 16, 0, 0);
}

__device__ __forceinline__ unsigned short bfbits(float f) {
  bf16 t = __float2bfloat16(f);
  return *reinterpret_cast<unsigned short*>(&t);
}

__device__ __forceinline__ unsigned int pk2(float lo, float hi) {
  return (unsigned int)bfbits(lo) | ((unsigned int)bfbits(hi) << 16);
}

// v_permlane32_swap_b32: a' = {a.lanes[0:31], b.lanes[0:31]},
//                        b' = {a.lanes[32:63], b.lanes[32:63]}
__device__ __forceinline__ void lswap(unsigned int& a, unsigned int& b) {
  asm("v_permlane32_swap_b32 %0, %1" : "+v"(a), "+v"(b));
}

// ------------------------------------------------------- convert f32->bf16
__global__ __launch_bounds__(256) void f32_to_bf16_k(const float* __restrict__ in,
                                                     bf16* __restrict__ out, size_t n) {
  const size_t i = ((size_t)blockIdx.x * 256 + threadIdx.x) * 4;
  if (i + 3 < n) {
    const float4 v = *(const float4*)(in + i);
    out[i + 0] = __float2bfloat16(v.x);
    out[i + 1] = __float2bfloat16(v.y);
    out[i + 2] = __float2bfloat16(v.z);
    out[i + 3] = __float2bfloat16(v.w);
  }
}

// ------------------------------------------- tiled transpose f32 -> bf16
__global__ __launch_bounds__(256) void tr_to_bf16_k(const float* __restrict__ in,
                                                    bf16* __restrict__ out,
                                                    int R, int C,
                                                    size_t inb, size_t outb) {
  __shared__ float tile[32][33];
  in  += (size_t)blockIdx.z * inb;
  out += (size_t)blockIdx.z * outb;
  const int r0 = blockIdx.y * 32, c0 = blockIdx.x * 32;
  const int tx = threadIdx.x & 31, ty = threadIdx.x >> 5;   // 32 x 8
#pragma unroll
  for (int i = 0; i < 4; ++i)
    tile[ty + i * 8][tx] = in[(size_t)(r0 + ty + i * 8) * C + c0 + tx];
  __syncthreads();
#pragma unroll
  for (int i = 0; i < 4; ++i)
    out[(size_t)(c0 + ty + i * 8) * R + r0 + tx] = __float2bfloat16(tile[tx][ty + i * 8]);
}

// ------------------------- 256xBN 8-phase bf16 MFMA GEMM (T1+T2+T3+T4+T5)
// BM=256, BN in {256,128}, BK=64, 512 threads = 8 waves (2M x 4N),
// per-wave C = 128 x (BN/4).
// LDS: A [2 dbuf][256][64] (64 KiB) + B [2 dbuf][BN][64] (BN/4 KiB).
// FULL 3-bit seg swizzle (R9): stored (row, seg) holds global
// (row, seg ^ (row&7)); pre-swizzled GLOBAL source col (linear LDS dest,
// rule 21) + swizzled ds_read seg -> b128 reads conflict-free
// (SQ_LDS_BANK_CONFLICT = 0 measured, R11).
// BN=256: 4 phases/tile (16 MFMA each). BN=128: 2 phases/tile (16 MFMA
// each; 4-phase left 8 MFMA between barriers -> barrier-bound).
// R12: ALL K=1024 / N<=4096 GEMMs use BN=128 -- the BN=256 128KiB-LDS
// variant forces 1 block/CU and a non-integral round count (QKV: 384
// blocks = 1.5 rounds, <=75% CU-time; MfmaUtil 21.8% measured). BN=128
// grids are exact multiples of 256 (QKV 768 = 3 rounds, FF1 1024 = 4).
// Counted s_waitcnt vmcnt(2*BH) once per tile (keeps B(u+2) in flight
// across barriers; never drains to 0 in the main loop). BH = BN/128.
// MODE 0 (QKV): bf16 out, Q scaled, V transposed into Vout. MODE 1: +bias,
// f32 out. MODE 2: +bias, relu, bf16 out.
template <int MODE, int BN>
__global__ __launch_bounds__(512, 2) void gemmT(const bf16* __restrict__ A,
                                                const bf16* __restrict__ B,
                                                const float* __restrict__ bias,
                                                float* __restrict__ Cf,
                                                bf16* __restrict__ Cb,
                                                bf16* __restrict__ Vout,
                                                int M, int N, int K) {
  constexpr int NF = BN / 64;    // per-wave 16-col N frags
  constexpr int BH = BN / 128;   // gld_lds16 per thread per B half-stage
  __shared__ __attribute__((aligned(16))) bf16 AS[2][256 * 64];
  __shared__ __attribute__((aligned(16))) bf16 BS[2][BN * 64];

  const int tid  = threadIdx.x;
  const int wid  = tid >> 6;
  const int lane = tid & 63;
  const int l16  = lane & 15;
  const int quad = lane >> 4;
  const int wm   = wid >> 2;        // 0..1  (M half)
  const int wn   = wid & 3;         // 0..3  (N quarter)

  // XCD-aware chunked swizzle (all launches have nwg % 8 == 0)
  const int gx  = gridDim.x;
  const int nwg = gx * gridDim.y;
  int lin = blockIdx.y * gx + blockIdx.x;
  lin = (lin & 7) * (nwg >> 3) + (lin >> 3);
  const int bm = (lin / gx) * 256;
  const int bn = (lin % gx) * BN;

  // staging map: linear dest byte d0 = tid*16 (= row sr, seg tid&7);
  // SOURCE col chunk pre-swizzled by the same involution seg ^ (row&7)
  const int sr   = tid >> 3;                        // dest row 0..63
  const int scol = ((tid & 7) ^ (sr & 7)) << 3;     // source element col
  const bf16* Asrc = A + (size_t)(bm + sr) * K + scol;
  const bf16* Bsrc = B + (size_t)(bn + sr) * K + scol;
  char* const AW0 = (char*)&AS[0][0] + wid * 1024;
  char* const AW1 = (char*)&AS[1][0] + wid * 1024;
  char* const BW0 = (char*)&BS[0][0] + wid * 1024;
  char* const BW1 = (char*)&BS[1][0] + wid * 1024;

  // fragment-read map: global (row, chunk cg=kk*4+quad) lives at LDS byte
  // row*128 + (cg ^ (row&7))*16; row&7 == l16&7 for all fragment rows.
  // seg bits are 4-6, so the kk step is XOR (kk<<6), not +kk*64.
  const int sq  = (quad ^ (l16 & 7)) << 4;
  const int rdA = l16 * 128 + sq;                      // + wm*16384 + mrow*2048, ^(kk<<6)
  const int rdB = wn * (BN / 4) * 128 + l16 * 128 + sq; // + nf*2048, ^(kk<<6)

#define STAGE_A2(dst, src) \
  do { gld_lds16((src), (dst)); gld_lds16((src) + (size_t)64 * K, (dst) + 8192); } while (0)
#define STAGE_BH(dst, src) \
  do { gld_lds16((src), (dst)); \
       if constexpr (BH == 2) gld_lds16((src) + (size_t)64 * K, (dst) + 8192); } while (0)
#define WAIT_B_INFLIGHT() \
  do { if constexpr (BN == 256) asm volatile("s_waitcnt vmcnt(4)" ::: "memory"); \
       else                     asm volatile("s_waitcnt vmcnt(2)" ::: "memory"); } while (0)

  f4v acc[8][NF];
#pragma unroll
  for (int i = 0; i < 8; ++i)
#pragma unroll
    for (int j = 0; j < NF; ++j) acc[i][j] = (f4v){0.f, 0.f, 0.f, 0.f};

  const int NT = K >> 6;

  // ---- prologue: A(0), B(0) -> buf0; B(1) -> buf1 (A(1) staged during tile 0)
  STAGE_A2(AW0,         Asrc);
  STAGE_A2(AW0 + 16384, Asrc + (size_t)128 * K);
  STAGE_BH(BW0,             Bsrc);
  STAGE_BH(BW0 + BH * 8192, Bsrc + (size_t)(BH * 64) * K);
  STAGE_BH(BW1,             Bsrc + 64);
  STAGE_BH(BW1 + BH * 8192, Bsrc + (size_t)(BH * 64) * K + 64);
  WAIT_B_INFLIGHT();   // A(0)+B(0) resident, B(1) in flight
  asm volatile("s_barrier" ::: "memory");

  s8v bfrag[NF][2];   // N-frags held in registers across the phases of a tile
  for (int u = 0; u < NT; ++u) {
    const int bsel = u & 1;
    const char* AsB = (const char*)&AS[bsel][0];
    const char* BsB = (const char*)&BS[bsel][0];
    char* const AWn = bsel ? AW0 : AW1;   // A(u+1) -> other buffer
    char* const BWc = bsel ? BW1 : BW0;   // B(u+2) -> current buffer
    const bf16* An = Asrc + (size_t)(u + 1) * 64;
    const bf16* Bn = Bsrc + (size_t)(u + 2) * 64;

    if constexpr (BN == 256) {
#pragma unroll
      for (int p = 0; p < 4; ++p) {
        s8v afrag[2][2];
#pragma unroll
        for (int j = 0; j < 2; ++j)
#pragma unroll
          for (int kk = 0; kk < 2; ++kk)
            afrag[j][kk] = *(const s8v*)(AsB +
                ((wm * 16384 + (p * 2 + j) * 2048 + rdA) ^ (kk << 6)));
        if (p == 0) {
#pragma unroll
          for (int nf = 0; nf < NF; ++nf)
#pragma unroll
            for (int kk = 0; kk < 2; ++kk)
              bfrag[nf][kk] = *(const s8v*)(BsB + ((nf * 2048 + rdB) ^ (kk << 6)));
        }
        if (p == 0 && u + 1 < NT) STAGE_A2(AWn,         An);
        if (p == 1 && u + 1 < NT) STAGE_A2(AWn + 16384, An + (size_t)128 * K);
        if (p == 2 && u + 2 < NT) STAGE_BH(BWc,             Bn);
        if (p == 3 && u + 2 < NT) STAGE_BH(BWc + BH * 8192, Bn + (size_t)(BH * 64) * K);
        asm volatile("s_barrier" ::: "memory");
        asm volatile("s_waitcnt lgkmcnt(0)" ::: "memory");
        __builtin_amdgcn_sched_barrier(0);
        __builtin_amdgcn_s_setprio(1);
#pragma unroll
        for (int kk = 0; kk < 2; ++kk)
#pragma unroll
          for (int j = 0; j < 2; ++j)
#pragma unroll
            for (int nf = 0; nf < NF; ++nf)
              acc[p * 2 + j][nf] = __builtin_amdgcn_mfma_f32_16x16x32_bf16(
                  afrag[j][kk], bfrag[nf][kk], acc[p * 2 + j][nf], 0, 0, 0);
        __builtin_amdgcn_s_setprio(0);
        if (p == 3) {
          if (u + 2 < NT) WAIT_B_INFLIGHT();
          else            asm volatile("s_waitcnt vmcnt(0)" ::: "memory");
        }
        asm volatile("s_barrier" ::: "memory");
      }
    } else {
      // ---- 2-phase schedule (BN=128): 16 MFMA per phase, 4 barriers/tile
#pragma unroll
      for (int p2 = 0; p2 < 2; ++p2) {
        s8v afrag[4][2];
#pragma unroll
        for (int j = 0; j < 4; ++j)
#pragma unroll
          for (int kk = 0; kk < 2; ++kk)
            afrag[j][kk] = *(const s8v*)(AsB +
                ((wm * 16384 + (p2 * 4 + j) * 2048 + rdA) ^ (kk << 6)));
        if (p2 == 0) {
#pragma unroll
          for (int nf = 0; nf < NF; ++nf)
#pragma unroll
            for (int kk = 0; kk < 2; ++kk)
              bfrag[nf][kk] = *(const s8v*)(BsB + ((nf * 2048 + rdB) ^ (kk << 6)));
        }
        if (p2 == 0 && u + 1 < NT) {
          STAGE_A2(AWn,         An);
          STAGE_A2(AWn + 16384, An + (size_t)128 * K);
        }
        if (p2 == 1 && u + 2 < NT) {
          STAGE_BH(BWc,             Bn);
          STAGE_BH(BWc + BH * 8192, Bn + (size_t)(BH * 64) * K);
        }
        asm volatile("s_barrier" ::: "memory");
        asm volatile("s_waitcnt lgkmcnt(0)" ::: "memory");
        __builtin_amdgcn_sched_barrier(0);
        __builtin_amdgcn_s_setprio(1);
#pragma unroll
        for (int kk = 0; kk < 2; ++kk)
#pragma unroll
          for (int j = 0; j < 4; ++j)
#pragma unroll
            for (int nf = 0; nf < NF; ++nf)
              acc[p2 * 4 + j][nf] = __builtin_amdgcn_mfma_f32_16x16x32_bf16(
                  afrag[j][kk], bfrag[nf][kk], acc[p2 * 4 + j][nf], 0, 0, 0);
        __builtin_amdgcn_s_setprio(0);
        if (p2 == 1) {
          if (u + 2 < NT) WAIT_B_INFLIGHT();
          else            asm volatile("s_waitcnt vmcnt(0)" ::: "memory");
        }
        asm volatile("s_barrier" ::: "memory");
      }
    }
  }
#undef STAGE_A2
#undef STAGE_BH
#undef WAIT_B_INFLIGHT

  // ---- epilogue (lane->C mapping: col=l16, row=quad*4+r)
  const size_t ldc = (size_t)N;
#pragma unroll
  for (int mf = 0; mf < 8; ++mf) {
#pragma unroll
    for (int nf = 0; nf < NF; ++nf) {
      const int col  = bn + wn * (BN / 4) + nf * 16 + l16;
      const int row0 = bm + wm * 128 + mf * 16 + quad * 4;
      if (MODE == 0) {
        if (col < 2048) {
          const float sc = (col < 1024) ? QSCALE : 1.0f;
#pragma unroll
          for (int r = 0; r < 4; ++r)
            Cb[(size_t)(row0 + r) * ldc + col] = __float2bfloat16(acc[mf][nf][r] * sc);
        } else {
          ushort4 pk;
          pk.x = bfbits(acc[mf][nf][0]);
          pk.y = bfbits(acc[mf][nf][1]);
          pk.z = bfbits(acc[mf][nf][2]);
          pk.w = bfbits(acc[mf][nf][3]);
          const int bb = row0 >> 11, t = row0 & 2047;
          *(ushort4*)&Vout[((size_t)(bb * 1024 + col - 2048)) * 2048 + t] = pk;
        }
      } else {
        const float bv = bias[col];
#pragma unroll
        for (int r = 0; r < 4; ++r) {
          const float v = acc[mf][nf][r] + bv;
          if (MODE == 1) Cf[(size_t)(row0 + r) * ldc + col] = v;
          else           Cb[(size_t)(row0 + r) * ldc + col] = __float2bfloat16(fmaxf(v, 0.f));
        }
      }
    }
  }
}

// -------------------------------------------------- bf16 MFMA flash attention
// S^T formulation (32x32x16). 1024 blocks x 256 thr, ONE q-tile per block
// (4 blocks/CU TLP). Balanced qt map (R8): rows {15-t, 8+t, 4+t, 3-t}.
// Counted-vmcnt double buffering (T4): per tile
//   [issue 4 gld -> nb][vmcnt(4)][s_barrier][compute cb][s_barrier]
// GUARD (R11): compute block wrapped in wave-uniform `kt*64 <= qmax_w` --
// without it kmmax goes NEGATIVE for waves whose q-range ends before this
// k-tile and the unconditional pmax tree reads uninitialized sacc -> NaN.
// Barriers remain OUTSIDE the guard (uniform).
// VALU cuts (R10): hoisted ZERO C-in for first K-slice; tree-reduced
// pmax/rs (depth 32 -> ~5); s_setprio(1) around MFMA clusters (T5).
// P in registers (pk2 + permlane32_swap, T12); defer-max (T13, THR=8 log2).
// launch_bounds (256,3): relaxed-cap regime, zero spill (R3/R4).
__global__ __launch_bounds__(256, 3) void attn_mfma(const bf16* __restrict__ qkv,
                                                    const bf16* __restrict__ vtg,
                                                    bf16* __restrict__ o) {
  __shared__ __attribute__((aligned(16))) bf16 KsS[2][64 * 64];  // [buf][key][d(swz)]
  __shared__ __attribute__((aligned(16))) bf16 VtS[2][64 * 64];  // [buf][d][key(swz)]
  __shared__ __attribute__((aligned(16))) float tS[128];         // alpha/l transpose

  const int tid  = threadIdx.x;
  const int w    = tid >> 6;
  const int lane = tid & 63;
  const int l32  = lane & 31;
  const int hi   = lane >> 5;
  const int xq   = l32 & 7;            // reader-side swizzle key

  // balanced qt decomposition (1024 blocks)
  const int lin = blockIdx.x;
  const int q2  = lin >> 8;            // 0..3
  const int rr  = lin & 255;
  const int tq  = rr >> 6;             // 0..3
  const int bh  = rr & 63;
  const int b   = bh & 3;
  const int h   = bh >> 2;
  const int qt  = (q2 == 0) ? (15 - tq)
                : (q2 == 1) ? (8 + tq)
                : (q2 == 2) ? (4 + tq)
                            : (3 - tq);

  const bf16* qbase = qkv + (size_t)b * 2048 * 3072 + h * 64;
  const bf16* kbase = qbase + 1024;
  const bf16* vbase = vtg + (size_t)(b * 1024 + h * 64) * 2048;

  // staging map: lane -> row sub-index + swizzled source segment
  const int rsub = lane >> 3;          // 0..7
  const int sseg = (lane & 7) ^ rsub;  // source seg (dest seg = lane&7 at row rsub)
  const int d0 = (w * 16) * 64;        // per-wave LDS dest offsets (elems)
  const int d1 = (w * 16 + 8) * 64;

  const int nkt = 2 * qt + 2;                // even, >= 2
  const int qmin_w = qt * 128 + w * 32;
  const int qmax_w = qmin_w + 31;
  const int q_lane = qmin_w + l32;

  // Q B-fragments [n=query l32][k=kstep*16+hi*8+j]
  s8v qf[4];
#pragma unroll
  for (int ks = 0; ks < 4; ++ks)
    qf[ks] = *(const s8v*)(qbase + (size_t)q_lane * 3072 + ks * 16 + hi * 8);

  float m_run = -1.0e38f, l_run = 0.f;
  f16v oacc[2];
#pragma unroll
  for (int dn = 0; dn < 2; ++dn)
#pragma unroll
    for (int r = 0; r < 16; ++r) oacc[dn][r] = 0.f;

  // hoisted zero C-in for the first K-slice MFMA of each tile
  f16v z16;
#pragma unroll
  for (int r = 0; r < 16; ++r) z16[r] = 0.f;

  // global staging pointers (tile 0)
  const bf16* kg = kbase + (size_t)(w * 16 + rsub) * 3072 + sseg * 8;
  const bf16* vg = vbase + (size_t)(w * 16 + rsub) * 2048 + sseg * 8;

  // ---- prologue: issue tile 0 into buf 0 (stays in flight; waited in-loop)
  gld_lds16(kg,                    &KsS[0][d0]);
  gld_lds16(kg + (size_t)8 * 3072, &KsS[0][d1]);
  gld_lds16(vg,                    &VtS[0][d0]);
  gld_lds16(vg + (size_t)8 * 2048, &VtS[0][d1]);
  kg += (size_t)64 * 3072; vg += 64;

  for (int kt = 0; kt < nkt; ++kt) {
    const int cb = kt & 1;

    // ---- issue async loads for tile kt+1, then wait only for tile kt
    if (kt + 1 < nkt) {
      const int nb = cb ^ 1;
      gld_lds16(kg,                    &KsS[nb][d0]);
      gld_lds16(kg + (size_t)8 * 3072, &KsS[nb][d1]);
      gld_lds16(vg,                    &VtS[nb][d0]);
      gld_lds16(vg + (size_t)8 * 2048, &VtS[nb][d1]);
      kg += (size_t)64 * 3072; vg += 64;
      asm volatile("s_waitcnt vmcnt(4)" ::: "memory");   // tile kt resident
    } else {
      asm volatile("s_waitcnt vmcnt(0)" ::: "memory");   // last tile: drain
    }
    asm volatile("s_barrier" ::: "memory");   // all waves: buf cb complete

    if (kt * 64 <= qmax_w) {
      const int kmmax = min(1, (qmax_w - kt * 64) >> 5);
      const bool diag = (kt * 64 + 63 > qmin_w);

      // ---- S^T = K · Q^T  (row = key, col = query); C-in = hoisted zero
      f16v sacc[2];
      __builtin_amdgcn_s_setprio(1);
      for (int km = 0; km <= kmmax; ++km) {
        {
          const s8v kf = *(const s8v*)&KsS[cb][(km * 32 + l32) * 64 +
                                               ((hi ^ xq) << 3)];
          sacc[km] = __builtin_amdgcn_mfma_f32_32x32x16_bf16(kf, qf[0], z16, 0, 0, 0);
        }
#pragma unroll
        for (int ks = 1; ks < 4; ++ks) {
          const s8v kf = *(const s8v*)&KsS[cb][(km * 32 + l32) * 64 +
                                               (((2 * ks + hi) ^ xq) << 3)];
          sacc[km] = __builtin_amdgcn_mfma_f32_32x32x16_bf16(kf, qf[ks], sacc[km], 0, 0, 0);
        }
      }
      __builtin_amdgcn_s_setprio(0);

      if (diag) {
        for (int km = 0; km <= kmmax; ++km)
#pragma unroll
          for (int r = 0; r < 16; ++r) {
            const int key = kt * 64 + km * 32 + (r & 3) + 8 * (r >> 2) + 4 * hi;
            if (key > q_lane) sacc[km][r] = -3.0e38f;
          }
      }

      // ---- per-query max: tree reduce (depth ~5) + one cross-half shuffle
      float pmax;
      {
        float a[8];
#pragma unroll
        for (int i = 0; i < 8; ++i)
          a[i] = fmaxf(sacc[0][2 * i], sacc[0][2 * i + 1]);
        if (kmmax) {
#pragma unroll
          for (int i = 0; i < 8; ++i)
            a[i] = fmaxf(a[i], fmaxf(sacc[1][2 * i], sacc[1][2 * i + 1]));
        }
        const float b0 = fmaxf(fmaxf(a[0], a[1]), fmaxf(a[2], a[3]));
        const float b1 = fmaxf(fmaxf(a[4], a[5]), fmaxf(a[6], a[7]));
        pmax = fmaxf(b0, b1);
      }
      pmax = fmaxf(pmax, __shfl_xor(pmax, 32));

      // ---- defer-max: only rescale when the max actually grows (> THR=8)
      float mref = m_run;
      if (!__all(pmax <= m_run + 8.f)) {
        const float mnew = fmaxf(m_run, pmax);
        const float alpha = __builtin_amdgcn_exp2f(m_run - mnew);
        m_run = mnew; mref = mnew;
        l_run *= alpha;
        // alpha: l32-convention -> row-register convention via LDS (wave-private)
        tS[w * 32 + l32] = alpha;
        f4v aF[4];
#pragma unroll
        for (int g2 = 0; g2 < 4; ++g2)
          aF[g2] = *(const f4v*)&tS[w * 32 + g2 * 8 + hi * 4];
#pragma unroll
        for (int dn = 0; dn < 2; ++dn)
#pragma unroll
          for (int r = 0; r < 16; ++r) oacc[dn][r] *= aF[r >> 2][r & 3];
      }

      // ---- P = exp2(S - mref), packed to bf16 A-fragments IN REGISTERS:
      // lane (l32,hi') holds keys (r&3)+8*(r>>2)+4*hi'; permlane32_swap
      // merges the two lane-halves into contiguous 8-key fragments for PV.
      float rs = 0.f;
      s8v pfr[4];
#pragma unroll
      for (int km = 0; km < 2; ++km)
        if (km <= kmmax) {
          float pv[16];
#pragma unroll
          for (int r = 0; r < 16; ++r)
            pv[r] = __builtin_amdgcn_exp2f(sacc[km][r] - mref);
          // tree-sum (depth 4) instead of a 16-deep serial chain
          const float s0 = (pv[0] + pv[1]) + (pv[2] + pv[3]);
          const float s1 = (pv[4] + pv[5]) + (pv[6] + pv[7]);
          const float s2 = (pv[8] + pv[9]) + (pv[10] + pv[11]);
          const float s3 = (pv[12] + pv[13]) + (pv[14] + pv[15]);
          rs += (s0 + s1) + (s2 + s3);
          unsigned int u0 = pk2(pv[0], pv[1]),  u1 = pk2(pv[2], pv[3]);
          unsigned int u2 = pk2(pv[4], pv[5]),  u3 = pk2(pv[6], pv[7]);
          lswap(u0, u2); lswap(u1, u3);
          u4v f0 = (u4v){u0, u1, u2, u3};
          pfr[2 * km] = *(s8v*)&f0;
          unsigned int v0 = pk2(pv[8], pv[9]),   v1 = pk2(pv[10], pv[11]);
          unsigned int v2 = pk2(pv[12], pv[13]), v3 = pk2(pv[14], pv[15]);
          lswap(v0, v2); lswap(v1, v3);
          u4v f1 = (u4v){v0, v1, v2, v3};
          pfr[2 * km + 1] = *(s8v*)&f1;
        }
      rs += __shfl_xor(rs, 32);
      l_run += rs;

      // ---- O += P · V  (A = P in regs, B = V^T rows=d, swizzled)
      __builtin_amdgcn_s_setprio(1);
#pragma unroll
      for (int ks = 0; ks < 4; ++ks)
        if ((ks >> 1) <= kmmax) {
#pragma unroll
          for (int dn = 0; dn < 2; ++dn) {
            const s8v vf = *(const s8v*)&VtS[cb][(dn * 32 + l32) * 64 +
                                                 (((2 * ks + hi) ^ xq) << 3)];
            oacc[dn] = __builtin_amdgcn_mfma_f32_32x32x16_bf16(pfr[ks], vf, oacc[dn], 0, 0, 0);
          }
        }
      __builtin_amdgcn_s_setprio(0);
    }
    asm volatile("s_barrier" ::: "memory");   // reads of cb done before reuse
  }

  // ---- epilogue: transpose l, divide, store
  tS[w * 32 + l32] = l_run;
  f4v lF[4];
#pragma unroll
  for (int g2 = 0; g2 < 4; ++g2)
    lF[g2] = *(const f4v*)&tS[w * 32 + g2 * 8 + hi * 4];

#pragma unroll
  for (int r = 0; r < 16; ++r) {
    const float inv = __builtin_amdgcn_rcpf(lF[r >> 2][r & 3]);
    const int row = qt * 128 + w * 32 + (r & 3) + 8 * (r >> 2) + 4 * hi;
    bf16* dst = o + ((size_t)b * 2048 + row) * 1024 + h * 64 + l32;
    dst[0]  = __float2bfloat16(oacc[0][r] * inv);
    dst[32] = __float2bfloat16(oacc[1][r] * inv);
  }
}

// ------------------------------------------- LayerNorm(ddof=1) + residual
__global__ __launch_bounds__(256) void ln_res(const float* __restrict__ xres,
                                              const float* __restrict__ t,
                                              float* __restrict__ xo,
                                              bf16* __restrict__ xob) {
  __shared__ float red[2][4];
  const int tid = threadIdx.x;
  const size_t base = (size_t)blockIdx.x * 1024;
  float v[4];
  float s = 0.f;
#pragma unroll
  for (int i = 0; i < 4; ++i) { v[i] = t[base + tid + i * 256]; s += v[i]; }
#pragma unroll
  for (int off = 32; off > 0; off >>= 1) s += __shfl_xor(s, off, 64);
  if ((tid & 63) == 0) red[0][tid >> 6] = s;
  __syncthreads();
  const float mean = (red[0][0] + red[0][1] + red[0][2] + red[0][3]) * (1.f / 1024.f);
  float ss = 0.f;
#pragma unroll
  for (int i = 0; i < 4; ++i) { const float d = v[i] - mean; ss += d * d; }
#pragma unroll
  for (int off = 32; off > 0; off >>= 1) ss += __shfl_xor(ss, off, 64);
  if ((tid & 63) == 0) red[1][tid >> 6] = ss;
  __syncthreads();
  const float var = (red[1][0] + red[1][1] + red[1][2] + red[1][3]) * (1.f / 1023.f);
  const float rstd = rsqrtf(var + 1e-5f);
#pragma unroll
  for (int i = 0; i < 4; ++i) {
    const size_t idx = base + tid + i * 256;
    const float r = xres[idx] + (v[i] - mean) * rstd;
    xo[idx] = r;
    if (xob) xob[idx] = __float2bfloat16(r);
  }
}

// ----------------------------------------------------------------- launch
extern "C" void kernel_launch(void* const* d_in, const int* in_sizes, int n_in,
                              void* d_out, int out_size, void* d_ws, size_t ws_size,
                              hipStream_t stream) {
  const float* x  = (const float*)d_in[0];
  const float* Wq = (const float*)d_in[1];
  const float* Wk = (const float*)d_in[2];
  const float* Wv = (const float*)d_in[3];
  const float* Wo = (const float*)d_in[4];
  const float* bo = (const float*)d_in[5];
  const float* W1 = (const float*)d_in[6];
  const float* b1 = (const float*)d_in[7];
  const float* W2 = (const float*)d_in[8];
  const float* b2 = (const float*)d_in[9];
  float* out = (float*)d_out;

  // ---- workspace map (no overlaps among simultaneously-live buffers)
  char* ws = (char*)d_ws;
  bf16* qkv_bf = (bf16*)(ws);                    //         0 .. 50,331,648  (48 MB; V cols unused)
  bf16* x_bf   = (bf16*)(ws + 50331648);         //  .. 67,108,864  (16 MB)
  bf16* WqkvT  = (bf16*)(ws + 67108864);         //  .. 73,400,320  (6 MB)
  bf16* WoT    = (bf16*)(ws + 73400320);         //  .. 75,497,472  (2 MB)
  bf16* W1T    = (bf16*)(ws + 75497472);         //  .. 83,886,080  (8 MB)
  bf16* W2T    = (bf16*)(ws + 83886080);         //  .. 92,274,688  (8 MB)
  bf16* o_bf   = (bf16*)(ws + 92274688);         //  .. 109,051,904 (16 MB)
  float* attn  = (float*)(ws + 109051904);       //  .. 142,606,336 (32 MB)
  float* x1    = (float*)(ws + 142606336);       //  .. 176,160,768 (32 MB)
  bf16* x1b    = (bf16*)(ws + 176160768);        //  .. 192,937,984 (16 MB)
  bf16* vt     = (bf16*)(ws + 192937984);        //  .. 209,715,200 (16 MB, V transposed)
  bf16* h1     = (bf16*)(ws);                    // 64 MB, reuses qkv_bf+x_bf (dead by FF)
  float* ff    = (float*)(ws + 109051904);       // 32 MB, reuses attn (dead after ln_res#1)

  // ---- input conversion / weight packing
  f32_to_bf16_k<<<8192, 256, 0, stream>>>(x, x_bf, (size_t)8388608);
  tr_to_bf16_k<<<dim3(2, 32, 16), 256, 0, stream>>>(Wq, WqkvT,               1024, 64,   65536, 65536);
  tr_to_bf16_k<<<dim3(2, 32, 16), 256, 0, stream>>>(Wk, WqkvT + 1024 * 1024, 1024, 64,   65536, 65536);
  tr_to_bf16_k<<<dim3(2, 32, 16), 256, 0, stream>>>(Wv, WqkvT + 2048 * 1024, 1024, 64,   65536, 65536);
  tr_to_bf16_k<<<dim3(32, 32, 1), 256, 0, stream>>>(Wo, WoT,                 1024, 1024, 0, 0);
  tr_to_bf16_k<<<dim3(128, 32, 1), 256, 0, stream>>>(W1, W1T,                1024, 4096, 0, 0);
  tr_to_bf16_k<<<dim3(32, 128, 1), 256, 0, stream>>>(W2, W2T,                4096, 1024, 0, 0);

  // ---- QKV projection (256x128 2-phase; 768 blocks = 3 exact rounds)
  gemmT<0, 128><<<dim3(24, 32), 512, 0, stream>>>(x_bf, WqkvT, nullptr, nullptr, qkv_bf, vt, 8192, 3072, 1024);

  // ---- MFMA flash attention (1024 balanced blocks, counted-vmcnt dbuf)
  attn_mfma<<<1024, 256, 0, stream>>>(qkv_bf, vt, o_bf);

  // ---- output projection + bias (256x128 2-phase, 256 blocks = 1 round)
  gemmT<1, 128><<<dim3(8, 32), 512, 0, stream>>>(o_bf, WoT, bo, attn, nullptr, nullptr, 8192, 1024, 1024);

  // ---- x1 = x + LN(attn)
  ln_res<<<8192, 256, 0, stream>>>(x, attn, x1, x1b);

  // ---- FF1 (256x128 2-phase, bias+relu; 1024 blocks = 4 exact rounds)
  gemmT<2, 128><<<dim3(32, 32), 512, 0, stream>>>(x1b, W1T, b1, nullptr, h1, nullptr, 8192, 4096, 1024);

  // ---- FF2 (256x128 2-phase)
  gemmT<1, 128><<<dim3(8, 32), 512, 0, stream>>>(h1, W2T, b2, ff, nullptr, nullptr, 8192, 1024, 4096);

  // ---- out = x1 + LN(ff)
  ln_res<<<8192, 256, 0, stream>>>(x1, ff, out, nullptr);
}

// Round 13
// 477.525 us; speedup vs baseline: 1.0515x; 1.0515x over previous
//
#include <hip/hip_runtime.h>
#include <hip/hip_bf16.h>

using bf16 = __hip_bfloat16;
typedef __attribute__((ext_vector_type(8))) short s8v;     // 8 bf16 in 4 VGPRs
typedef __attribute__((ext_vector_type(4))) float f4v;     // 16x16 mfma accumulator
typedef __attribute__((ext_vector_type(16))) float f16v;   // 32x32 mfma accumulator
typedef __attribute__((ext_vector_type(4))) unsigned int u4v;

#define QSCALE 0.18033688011112042f   /* 0.125 * log2(e) */

// ---------------------------------------------------------------- helpers
__device__ __forceinline__ void gld_lds16(const void* g, void* l) {
  __builtin_amdgcn_global_load_lds(
      (const __attribute__((address_space(1))) void*)g,
      (__attribute__((address_space(3))) void*)l, 16, 0, 0);
}

__device__ __forceinline__ unsigned short bfbits(float f) {
  bf16 t = __float2bfloat16(f);
  return *reinterpret_cast<unsigned short*>(&t);
}

__device__ __forceinline__ unsigned int pk2(float lo, float hi) {
  return (unsigned int)bfbits(lo) | ((unsigned int)bfbits(hi) << 16);
}

// v_permlane32_swap_b32: a' = {a.lanes[0:31], b.lanes[0:31]},
//                        b' = {a.lanes[32:63], b.lanes[32:63]}
__device__ __forceinline__ void lswap(unsigned int& a, unsigned int& b) {
  asm("v_permlane32_swap_b32 %0, %1" : "+v"(a), "+v"(b));
}

// ------------------------------------------------------- convert f32->bf16
__global__ __launch_bounds__(256) void f32_to_bf16_k(const float* __restrict__ in,
                                                     bf16* __restrict__ out, size_t n) {
  const size_t i = ((size_t)blockIdx.x * 256 + threadIdx.x) * 4;
  if (i + 3 < n) {
    const float4 v = *(const float4*)(in + i);
    out[i + 0] = __float2bfloat16(v.x);
    out[i + 1] = __float2bfloat16(v.y);
    out[i + 2] = __float2bfloat16(v.z);
    out[i + 3] = __float2bfloat16(v.w);
  }
}

// ------------------------------------------- tiled transpose f32 -> bf16
__global__ __launch_bounds__(256) void tr_to_bf16_k(const float* __restrict__ in,
                                                    bf16* __restrict__ out,
                                                    int R, int C,
                                                    size_t inb, size_t outb) {
  __shared__ float tile[32][33];
  in  += (size_t)blockIdx.z * inb;
  out += (size_t)blockIdx.z * outb;
  const int r0 = blockIdx.y * 32, c0 = blockIdx.x * 32;
  const int tx = threadIdx.x & 31, ty = threadIdx.x >> 5;   // 32 x 8
#pragma unroll
  for (int i = 0; i < 4; ++i)
    tile[ty + i * 8][tx] = in[(size_t)(r0 + ty + i * 8) * C + c0 + tx];
  __syncthreads();
#pragma unroll
  for (int i = 0; i < 4; ++i)
    out[(size_t)(c0 + ty + i * 8) * R + r0 + tx] = __float2bfloat16(tile[tx][ty + i * 8]);
}

// ------------------------- 256xBN 8-phase bf16 MFMA GEMM (T1+T2+T3+T4+T5)
// BM=256, BN in {256,128}, BK=64, 512 threads = 8 waves (2M x 4N),
// per-wave C = 128 x (BN/4).
// LDS: A [2 dbuf][256][64] (64 KiB) + B [2 dbuf][BN][64] (BN/4 KiB).
// FULL 3-bit seg swizzle (R9): stored (row, seg) holds global
// (row, seg ^ (row&7)); pre-swizzled GLOBAL source col (linear LDS dest,
// rule 21) + swizzled ds_read seg -> b128 reads conflict-free
// (SQ_LDS_BANK_CONFLICT = 0 measured, R11).
// BN=256: 4 phases/tile (16 MFMA each). BN=128: 2 phases/tile (16 MFMA
// each; 4-phase left 8 MFMA between barriers -> barrier-bound).
// Variant selection (R13, measured): BN=128 for N=1024 GEMMs (Wo, FF2)
// and QKV (fixes the 384-block=1.5-round quantization of BN=256);
// BN=256 for FF1 (N=4096: 512 blocks = 2 exact rounds already; BN=128
// doubled A-refetch -> FETCH 139.6 MB, 96us measured R12 -- reverted).
// Counted s_waitcnt vmcnt(2*BH) once per tile (keeps B(u+2) in flight
// across barriers; never drains to 0 in the main loop). BH = BN/128.
// MODE 0 (QKV): bf16 out, Q scaled, V transposed into Vout. MODE 1: +bias,
// f32 out. MODE 2: +bias, relu, bf16 out.
template <int MODE, int BN>
__global__ __launch_bounds__(512, 2) void gemmT(const bf16* __restrict__ A,
                                                const bf16* __restrict__ B,
                                                const float* __restrict__ bias,
                                                float* __restrict__ Cf,
                                                bf16* __restrict__ Cb,
                                                bf16* __restrict__ Vout,
                                                int M, int N, int K) {
  constexpr int NF = BN / 64;    // per-wave 16-col N frags
  constexpr int BH = BN / 128;   // gld_lds16 per thread per B half-stage
  __shared__ __attribute__((aligned(16))) bf16 AS[2][256 * 64];
  __shared__ __attribute__((aligned(16))) bf16 BS[2][BN * 64];

  const int tid  = threadIdx.x;
  const int wid  = tid >> 6;
  const int lane = tid & 63;
  const int l16  = lane & 15;
  const int quad = lane >> 4;
  const int wm   = wid >> 2;        // 0..1  (M half)
  const int wn   = wid & 3;         // 0..3  (N quarter)

  // XCD-aware chunked swizzle (all launches have nwg % 8 == 0)
  const int gx  = gridDim.x;
  const int nwg = gx * gridDim.y;
  int lin = blockIdx.y * gx + blockIdx.x;
  lin = (lin & 7) * (nwg >> 3) + (lin >> 3);
  const int bm = (lin / gx) * 256;
  const int bn = (lin % gx) * BN;

  // staging map: linear dest byte d0 = tid*16 (= row sr, seg tid&7);
  // SOURCE col chunk pre-swizzled by the same involution seg ^ (row&7)
  const int sr   = tid >> 3;                        // dest row 0..63
  const int scol = ((tid & 7) ^ (sr & 7)) << 3;     // source element col
  const bf16* Asrc = A + (size_t)(bm + sr) * K + scol;
  const bf16* Bsrc = B + (size_t)(bn + sr) * K + scol;
  char* const AW0 = (char*)&AS[0][0] + wid * 1024;
  char* const AW1 = (char*)&AS[1][0] + wid * 1024;
  char* const BW0 = (char*)&BS[0][0] + wid * 1024;
  char* const BW1 = (char*)&BS[1][0] + wid * 1024;

  // fragment-read map: global (row, chunk cg=kk*4+quad) lives at LDS byte
  // row*128 + (cg ^ (row&7))*16; row&7 == l16&7 for all fragment rows.
  // seg bits are 4-6, so the kk step is XOR (kk<<6), not +kk*64.
  const int sq  = (quad ^ (l16 & 7)) << 4;
  const int rdA = l16 * 128 + sq;                      // + wm*16384 + mrow*2048, ^(kk<<6)
  const int rdB = wn * (BN / 4) * 128 + l16 * 128 + sq; // + nf*2048, ^(kk<<6)

#define STAGE_A2(dst, src) \
  do { gld_lds16((src), (dst)); gld_lds16((src) + (size_t)64 * K, (dst) + 8192); } while (0)
#define STAGE_BH(dst, src) \
  do { gld_lds16((src), (dst)); \
       if constexpr (BH == 2) gld_lds16((src) + (size_t)64 * K, (dst) + 8192); } while (0)
#define WAIT_B_INFLIGHT() \
  do { if constexpr (BN == 256) asm volatile("s_waitcnt vmcnt(4)" ::: "memory"); \
       else                     asm volatile("s_waitcnt vmcnt(2)" ::: "memory"); } while (0)

  f4v acc[8][NF];
#pragma unroll
  for (int i = 0; i < 8; ++i)
#pragma unroll
    for (int j = 0; j < NF; ++j) acc[i][j] = (f4v){0.f, 0.f, 0.f, 0.f};

  const int NT = K >> 6;

  // ---- prologue: A(0), B(0) -> buf0; B(1) -> buf1 (A(1) staged during tile 0)
  STAGE_A2(AW0,         Asrc);
  STAGE_A2(AW0 + 16384, Asrc + (size_t)128 * K);
  STAGE_BH(BW0,             Bsrc);
  STAGE_BH(BW0 + BH * 8192, Bsrc + (size_t)(BH * 64) * K);
  STAGE_BH(BW1,             Bsrc + 64);
  STAGE_BH(BW1 + BH * 8192, Bsrc + (size_t)(BH * 64) * K + 64);
  WAIT_B_INFLIGHT();   // A(0)+B(0) resident, B(1) in flight
  asm volatile("s_barrier" ::: "memory");

  s8v bfrag[NF][2];   // N-frags held in registers across the phases of a tile
  for (int u = 0; u < NT; ++u) {
    const int bsel = u & 1;
    const char* AsB = (const char*)&AS[bsel][0];
    const char* BsB = (const char*)&BS[bsel][0];
    char* const AWn = bsel ? AW0 : AW1;   // A(u+1) -> other buffer
    char* const BWc = bsel ? BW1 : BW0;   // B(u+2) -> current buffer
    const bf16* An = Asrc + (size_t)(u + 1) * 64;
    const bf16* Bn = Bsrc + (size_t)(u + 2) * 64;

    if constexpr (BN == 256) {
#pragma unroll
      for (int p = 0; p < 4; ++p) {
        s8v afrag[2][2];
#pragma unroll
        for (int j = 0; j < 2; ++j)
#pragma unroll
          for (int kk = 0; kk < 2; ++kk)
            afrag[j][kk] = *(const s8v*)(AsB +
                ((wm * 16384 + (p * 2 + j) * 2048 + rdA) ^ (kk << 6)));
        if (p == 0) {
#pragma unroll
          for (int nf = 0; nf < NF; ++nf)
#pragma unroll
            for (int kk = 0; kk < 2; ++kk)
              bfrag[nf][kk] = *(const s8v*)(BsB + ((nf * 2048 + rdB) ^ (kk << 6)));
        }
        if (p == 0 && u + 1 < NT) STAGE_A2(AWn,         An);
        if (p == 1 && u + 1 < NT) STAGE_A2(AWn + 16384, An + (size_t)128 * K);
        if (p == 2 && u + 2 < NT) STAGE_BH(BWc,             Bn);
        if (p == 3 && u + 2 < NT) STAGE_BH(BWc + BH * 8192, Bn + (size_t)(BH * 64) * K);
        asm volatile("s_barrier" ::: "memory");
        asm volatile("s_waitcnt lgkmcnt(0)" ::: "memory");
        __builtin_amdgcn_sched_barrier(0);
        __builtin_amdgcn_s_setprio(1);
#pragma unroll
        for (int kk = 0; kk < 2; ++kk)
#pragma unroll
          for (int j = 0; j < 2; ++j)
#pragma unroll
            for (int nf = 0; nf < NF; ++nf)
              acc[p * 2 + j][nf] = __builtin_amdgcn_mfma_f32_16x16x32_bf16(
                  afrag[j][kk], bfrag[nf][kk], acc[p * 2 + j][nf], 0, 0, 0);
        __builtin_amdgcn_s_setprio(0);
        if (p == 3) {
          if (u + 2 < NT) WAIT_B_INFLIGHT();
          else            asm volatile("s_waitcnt vmcnt(0)" ::: "memory");
        }
        asm volatile("s_barrier" ::: "memory");
      }
    } else {
      // ---- 2-phase schedule (BN=128): 16 MFMA per phase, 4 barriers/tile
#pragma unroll
      for (int p2 = 0; p2 < 2; ++p2) {
        s8v afrag[4][2];
#pragma unroll
        for (int j = 0; j < 4; ++j)
#pragma unroll
          for (int kk = 0; kk < 2; ++kk)
            afrag[j][kk] = *(const s8v*)(AsB +
                ((wm * 16384 + (p2 * 4 + j) * 2048 + rdA) ^ (kk << 6)));
        if (p2 == 0) {
#pragma unroll
          for (int nf = 0; nf < NF; ++nf)
#pragma unroll
            for (int kk = 0; kk < 2; ++kk)
              bfrag[nf][kk] = *(const s8v*)(BsB + ((nf * 2048 + rdB) ^ (kk << 6)));
        }
        if (p2 == 0 && u + 1 < NT) {
          STAGE_A2(AWn,         An);
          STAGE_A2(AWn + 16384, An + (size_t)128 * K);
        }
        if (p2 == 1 && u + 2 < NT) {
          STAGE_BH(BWc,             Bn);
          STAGE_BH(BWc + BH * 8192, Bn + (size_t)(BH * 64) * K);
        }
        asm volatile("s_barrier" ::: "memory");
        asm volatile("s_waitcnt lgkmcnt(0)" ::: "memory");
        __builtin_amdgcn_sched_barrier(0);
        __builtin_amdgcn_s_setprio(1);
#pragma unroll
        for (int kk = 0; kk < 2; ++kk)
#pragma unroll
          for (int j = 0; j < 4; ++j)
#pragma unroll
            for (int nf = 0; nf < NF; ++nf)
              acc[p2 * 4 + j][nf] = __builtin_amdgcn_mfma_f32_16x16x32_bf16(
                  afrag[j][kk], bfrag[nf][kk], acc[p2 * 4 + j][nf], 0, 0, 0);
        __builtin_amdgcn_s_setprio(0);
        if (p2 == 1) {
          if (u + 2 < NT) WAIT_B_INFLIGHT();
          else            asm volatile("s_waitcnt vmcnt(0)" ::: "memory");
        }
        asm volatile("s_barrier" ::: "memory");
      }
    }
  }
#undef STAGE_A2
#undef STAGE_BH
#undef WAIT_B_INFLIGHT

  // ---- epilogue (lane->C mapping: col=l16, row=quad*4+r)
  const size_t ldc = (size_t)N;
#pragma unroll
  for (int mf = 0; mf < 8; ++mf) {
#pragma unroll
    for (int nf = 0; nf < NF; ++nf) {
      const int col  = bn + wn * (BN / 4) + nf * 16 + l16;
      const int row0 = bm + wm * 128 + mf * 16 + quad * 4;
      if (MODE == 0) {
        if (col < 2048) {
          const float sc = (col < 1024) ? QSCALE : 1.0f;
#pragma unroll
          for (int r = 0; r < 4; ++r)
            Cb[(size_t)(row0 + r) * ldc + col] = __float2bfloat16(acc[mf][nf][r] * sc);
        } else {
          ushort4 pk;
          pk.x = bfbits(acc[mf][nf][0]);
          pk.y = bfbits(acc[mf][nf][1]);
          pk.z = bfbits(acc[mf][nf][2]);
          pk.w = bfbits(acc[mf][nf][3]);
          const int bb = row0 >> 11, t = row0 & 2047;
          *(ushort4*)&Vout[((size_t)(bb * 1024 + col - 2048)) * 2048 + t] = pk;
        }
      } else {
        const float bv = bias[col];
#pragma unroll
        for (int r = 0; r < 4; ++r) {
          const float v = acc[mf][nf][r] + bv;
          if (MODE == 1) Cf[(size_t)(row0 + r) * ldc + col] = v;
          else           Cb[(size_t)(row0 + r) * ldc + col] = __float2bfloat16(fmaxf(v, 0.f));
        }
      }
    }
  }
}

// -------------------------------------------------- bf16 MFMA flash attention
// S^T formulation (32x32x16). 1024 blocks x 256 thr, ONE q-tile per block
// (4 blocks/CU TLP). Balanced qt map (R8): rows {15-t, 8+t, 4+t, 3-t}.
// Counted-vmcnt double buffering (T4): per tile
//   [issue 4 gld -> nb][vmcnt(4)][s_barrier][compute cb][s_barrier]
// GUARD (R11): compute block wrapped in wave-uniform `kt*64 <= qmax_w` --
// without it kmmax goes NEGATIVE for waves whose q-range ends before this
// k-tile and the unconditional pmax tree reads uninitialized sacc -> NaN.
// Barriers remain OUTSIDE the guard (uniform).
// VALU cuts (R10): hoisted ZERO C-in for first K-slice; tree-reduced
// pmax/rs (depth 32 -> ~5); s_setprio(1) around MFMA clusters (T5).
// P in registers (pk2 + permlane32_swap, T12); defer-max (T13, THR=8 log2).
// launch_bounds (256,3): relaxed-cap regime, zero spill (R3/R4).
__global__ __launch_bounds__(256, 3) void attn_mfma(const bf16* __restrict__ qkv,
                                                    const bf16* __restrict__ vtg,
                                                    bf16* __restrict__ o) {
  __shared__ __attribute__((aligned(16))) bf16 KsS[2][64 * 64];  // [buf][key][d(swz)]
  __shared__ __attribute__((aligned(16))) bf16 VtS[2][64 * 64];  // [buf][d][key(swz)]
  __shared__ __attribute__((aligned(16))) float tS[128];         // alpha/l transpose

  const int tid  = threadIdx.x;
  const int w    = tid >> 6;
  const int lane = tid & 63;
  const int l32  = lane & 31;
  const int hi   = lane >> 5;
  const int xq   = l32 & 7;            // reader-side swizzle key

  // balanced qt decomposition (1024 blocks)
  const int lin = blockIdx.x;
  const int q2  = lin >> 8;            // 0..3
  const int rr  = lin & 255;
  const int tq  = rr >> 6;             // 0..3
  const int bh  = rr & 63;
  const int b   = bh & 3;
  const int h   = bh >> 2;
  const int qt  = (q2 == 0) ? (15 - tq)
                : (q2 == 1) ? (8 + tq)
                : (q2 == 2) ? (4 + tq)
                            : (3 - tq);

  const bf16* qbase = qkv + (size_t)b * 2048 * 3072 + h * 64;
  const bf16* kbase = qbase + 1024;
  const bf16* vbase = vtg + (size_t)(b * 1024 + h * 64) * 2048;

  // staging map: lane -> row sub-index + swizzled source segment
  const int rsub = lane >> 3;          // 0..7
  const int sseg = (lane & 7) ^ rsub;  // source seg (dest seg = lane&7 at row rsub)
  const int d0 = (w * 16) * 64;        // per-wave LDS dest offsets (elems)
  const int d1 = (w * 16 + 8) * 64;

  const int nkt = 2 * qt + 2;                // even, >= 2
  const int qmin_w = qt * 128 + w * 32;
  const int qmax_w = qmin_w + 31;
  const int q_lane = qmin_w + l32;

  // Q B-fragments [n=query l32][k=kstep*16+hi*8+j]
  s8v qf[4];
#pragma unroll
  for (int ks = 0; ks < 4; ++ks)
    qf[ks] = *(const s8v*)(qbase + (size_t)q_lane * 3072 + ks * 16 + hi * 8);

  float m_run = -1.0e38f, l_run = 0.f;
  f16v oacc[2];
#pragma unroll
  for (int dn = 0; dn < 2; ++dn)
#pragma unroll
    for (int r = 0; r < 16; ++r) oacc[dn][r] = 0.f;

  // hoisted zero C-in for the first K-slice MFMA of each tile
  f16v z16;
#pragma unroll
  for (int r = 0; r < 16; ++r) z16[r] = 0.f;

  // global staging pointers (tile 0)
  const bf16* kg = kbase + (size_t)(w * 16 + rsub) * 3072 + sseg * 8;
  const bf16* vg = vbase + (size_t)(w * 16 + rsub) * 2048 + sseg * 8;

  // ---- prologue: issue tile 0 into buf 0 (stays in flight; waited in-loop)
  gld_lds16(kg,                    &KsS[0][d0]);
  gld_lds16(kg + (size_t)8 * 3072, &KsS[0][d1]);
  gld_lds16(vg,                    &VtS[0][d0]);
  gld_lds16(vg + (size_t)8 * 2048, &VtS[0][d1]);
  kg += (size_t)64 * 3072; vg += 64;

  for (int kt = 0; kt < nkt; ++kt) {
    const int cb = kt & 1;

    // ---- issue async loads for tile kt+1, then wait only for tile kt
    if (kt + 1 < nkt) {
      const int nb = cb ^ 1;
      gld_lds16(kg,                    &KsS[nb][d0]);
      gld_lds16(kg + (size_t)8 * 3072, &KsS[nb][d1]);
      gld_lds16(vg,                    &VtS[nb][d0]);
      gld_lds16(vg + (size_t)8 * 2048, &VtS[nb][d1]);
      kg += (size_t)64 * 3072; vg += 64;
      asm volatile("s_waitcnt vmcnt(4)" ::: "memory");   // tile kt resident
    } else {
      asm volatile("s_waitcnt vmcnt(0)" ::: "memory");   // last tile: drain
    }
    asm volatile("s_barrier" ::: "memory");   // all waves: buf cb complete

    if (kt * 64 <= qmax_w) {
      const int kmmax = min(1, (qmax_w - kt * 64) >> 5);
      const bool diag = (kt * 64 + 63 > qmin_w);

      // ---- S^T = K · Q^T  (row = key, col = query); C-in = hoisted zero
      f16v sacc[2];
      __builtin_amdgcn_s_setprio(1);
      for (int km = 0; km <= kmmax; ++km) {
        {
          const s8v kf = *(const s8v*)&KsS[cb][(km * 32 + l32) * 64 +
                                               ((hi ^ xq) << 3)];
          sacc[km] = __builtin_amdgcn_mfma_f32_32x32x16_bf16(kf, qf[0], z16, 0, 0, 0);
        }
#pragma unroll
        for (int ks = 1; ks < 4; ++ks) {
          const s8v kf = *(const s8v*)&KsS[cb][(km * 32 + l32) * 64 +
                                               (((2 * ks + hi) ^ xq) << 3)];
          sacc[km] = __builtin_amdgcn_mfma_f32_32x32x16_bf16(kf, qf[ks], sacc[km], 0, 0, 0);
        }
      }
      __builtin_amdgcn_s_setprio(0);

      if (diag) {
        for (int km = 0; km <= kmmax; ++km)
#pragma unroll
          for (int r = 0; r < 16; ++r) {
            const int key = kt * 64 + km * 32 + (r & 3) + 8 * (r >> 2) + 4 * hi;
            if (key > q_lane) sacc[km][r] = -3.0e38f;
          }
      }

      // ---- per-query max: tree reduce (depth ~5) + one cross-half shuffle
      float pmax;
      {
        float a[8];
#pragma unroll
        for (int i = 0; i < 8; ++i)
          a[i] = fmaxf(sacc[0][2 * i], sacc[0][2 * i + 1]);
        if (kmmax) {
#pragma unroll
          for (int i = 0; i < 8; ++i)
            a[i] = fmaxf(a[i], fmaxf(sacc[1][2 * i], sacc[1][2 * i + 1]));
        }
        const float b0 = fmaxf(fmaxf(a[0], a[1]), fmaxf(a[2], a[3]));
        const float b1 = fmaxf(fmaxf(a[4], a[5]), fmaxf(a[6], a[7]));
        pmax = fmaxf(b0, b1);
      }
      pmax = fmaxf(pmax, __shfl_xor(pmax, 32));

      // ---- defer-max: only rescale when the max actually grows (> THR=8)
      float mref = m_run;
      if (!__all(pmax <= m_run + 8.f)) {
        const float mnew = fmaxf(m_run, pmax);
        const float alpha = __builtin_amdgcn_exp2f(m_run - mnew);
        m_run = mnew; mref = mnew;
        l_run *= alpha;
        // alpha: l32-convention -> row-register convention via LDS (wave-private)
        tS[w * 32 + l32] = alpha;
        f4v aF[4];
#pragma unroll
        for (int g2 = 0; g2 < 4; ++g2)
          aF[g2] = *(const f4v*)&tS[w * 32 + g2 * 8 + hi * 4];
#pragma unroll
        for (int dn = 0; dn < 2; ++dn)
#pragma unroll
          for (int r = 0; r < 16; ++r) oacc[dn][r] *= aF[r >> 2][r & 3];
      }

      // ---- P = exp2(S - mref), packed to bf16 A-fragments IN REGISTERS:
      // lane (l32,hi') holds keys (r&3)+8*(r>>2)+4*hi'; permlane32_swap
      // merges the two lane-halves into contiguous 8-key fragments for PV.
      float rs = 0.f;
      s8v pfr[4];
#pragma unroll
      for (int km = 0; km < 2; ++km)
        if (km <= kmmax) {
          float pv[16];
#pragma unroll
          for (int r = 0; r < 16; ++r)
            pv[r] = __builtin_amdgcn_exp2f(sacc[km][r] - mref);
          // tree-sum (depth 4) instead of a 16-deep serial chain
          const float s0 = (pv[0] + pv[1]) + (pv[2] + pv[3]);
          const float s1 = (pv[4] + pv[5]) + (pv[6] + pv[7]);
          const float s2 = (pv[8] + pv[9]) + (pv[10] + pv[11]);
          const float s3 = (pv[12] + pv[13]) + (pv[14] + pv[15]);
          rs += (s0 + s1) + (s2 + s3);
          unsigned int u0 = pk2(pv[0], pv[1]),  u1 = pk2(pv[2], pv[3]);
          unsigned int u2 = pk2(pv[4], pv[5]),  u3 = pk2(pv[6], pv[7]);
          lswap(u0, u2); lswap(u1, u3);
          u4v f0 = (u4v){u0, u1, u2, u3};
          pfr[2 * km] = *(s8v*)&f0;
          unsigned int v0 = pk2(pv[8], pv[9]),   v1 = pk2(pv[10], pv[11]);
          unsigned int v2 = pk2(pv[12], pv[13]), v3 = pk2(pv[14], pv[15]);
          lswap(v0, v2); lswap(v1, v3);
          u4v f1 = (u4v){v0, v1, v2, v3};
          pfr[2 * km + 1] = *(s8v*)&f1;
        }
      rs += __shfl_xor(rs, 32);
      l_run += rs;

      // ---- O += P · V  (A = P in regs, B = V^T rows=d, swizzled)
      __builtin_amdgcn_s_setprio(1);
#pragma unroll
      for (int ks = 0; ks < 4; ++ks)
        if ((ks >> 1) <= kmmax) {
#pragma unroll
          for (int dn = 0; dn < 2; ++dn) {
            const s8v vf = *(const s8v*)&VtS[cb][(dn * 32 + l32) * 64 +
                                                 (((2 * ks + hi) ^ xq) << 3)];
            oacc[dn] = __builtin_amdgcn_mfma_f32_32x32x16_bf16(pfr[ks], vf, oacc[dn], 0, 0, 0);
          }
        }
      __builtin_amdgcn_s_setprio(0);
    }
    asm volatile("s_barrier" ::: "memory");   // reads of cb done before reuse
  }

  // ---- epilogue: transpose l, divide, store
  tS[w * 32 + l32] = l_run;
  f4v lF[4];
#pragma unroll
  for (int g2 = 0; g2 < 4; ++g2)
    lF[g2] = *(const f4v*)&tS[w * 32 + g2 * 8 + hi * 4];

#pragma unroll
  for (int r = 0; r < 16; ++r) {
    const float inv = __builtin_amdgcn_rcpf(lF[r >> 2][r & 3]);
    const int row = qt * 128 + w * 32 + (r & 3) + 8 * (r >> 2) + 4 * hi;
    bf16* dst = o + ((size_t)b * 2048 + row) * 1024 + h * 64 + l32;
    dst[0]  = __float2bfloat16(oacc[0][r] * inv);
    dst[32] = __float2bfloat16(oacc[1][r] * inv);
  }
}

// ------------------------------------------- LayerNorm(ddof=1) + residual
__global__ __launch_bounds__(256) void ln_res(const float* __restrict__ xres,
                                              const float* __restrict__ t,
                                              float* __restrict__ xo,
                                              bf16* __restrict__ xob) {
  __shared__ float red[2][4];
  const int tid = threadIdx.x;
  const size_t base = (size_t)blockIdx.x * 1024;
  float v[4];
  float s = 0.f;
#pragma unroll
  for (int i = 0; i < 4; ++i) { v[i] = t[base + tid + i * 256]; s += v[i]; }
#pragma unroll
  for (int off = 32; off > 0; off >>= 1) s += __shfl_xor(s, off, 64);
  if ((tid & 63) == 0) red[0][tid >> 6] = s;
  __syncthreads();
  const float mean = (red[0][0] + red[0][1] + red[0][2] + red[0][3]) * (1.f / 1024.f);
  float ss = 0.f;
#pragma unroll
  for (int i = 0; i < 4; ++i) { const float d = v[i] - mean; ss += d * d; }
#pragma unroll
  for (int off = 32; off > 0; off >>= 1) ss += __shfl_xor(ss, off, 64);
  if ((tid & 63) == 0) red[1][tid >> 6] = ss;
  __syncthreads();
  const float var = (red[1][0] + red[1][1] + red[1][2] + red[1][3]) * (1.f / 1023.f);
  const float rstd = rsqrtf(var + 1e-5f);
#pragma unroll
  for (int i = 0; i < 4; ++i) {
    const size_t idx = base + tid + i * 256;
    const float r = xres[idx] + (v[i] - mean) * rstd;
    xo[idx] = r;
    if (xob) xob[idx] = __float2bfloat16(r);
  }
}

// ----------------------------------------------------------------- launch
extern "C" void kernel_launch(void* const* d_in, const int* in_sizes, int n_in,
                              void* d_out, int out_size, void* d_ws, size_t ws_size,
                              hipStream_t stream) {
  const float* x  = (const float*)d_in[0];
  const float* Wq = (const float*)d_in[1];
  const float* Wk = (const float*)d_in[2];
  const float* Wv = (const float*)d_in[3];
  const float* Wo = (const float*)d_in[4];
  const float* bo = (const float*)d_in[5];
  const float* W1 = (const float*)d_in[6];
  const float* b1 = (const float*)d_in[7];
  const float* W2 = (const float*)d_in[8];
  const float* b2 = (const float*)d_in[9];
  float* out = (float*)d_out;

  // ---- workspace map (no overlaps among simultaneously-live buffers)
  char* ws = (char*)d_ws;
  bf16* qkv_bf = (bf16*)(ws);                    //         0 .. 50,331,648  (48 MB; V cols unused)
  bf16* x_bf   = (bf16*)(ws + 50331648);         //  .. 67,108,864  (16 MB)
  bf16* WqkvT  = (bf16*)(ws + 67108864);         //  .. 73,400,320  (6 MB)
  bf16* WoT    = (bf16*)(ws + 73400320);         //  .. 75,497,472  (2 MB)
  bf16* W1T    = (bf16*)(ws + 75497472);         //  .. 83,886,080  (8 MB)
  bf16* W2T    = (bf16*)(ws + 83886080);         //  .. 92,274,688  (8 MB)
  bf16* o_bf   = (bf16*)(ws + 92274688);         //  .. 109,051,904 (16 MB)
  float* attn  = (float*)(ws + 109051904);       //  .. 142,606,336 (32 MB)
  float* x1    = (float*)(ws + 142606336);       //  .. 176,160,768 (32 MB)
  bf16* x1b    = (bf16*)(ws + 176160768);        //  .. 192,937,984 (16 MB)
  bf16* vt     = (bf16*)(ws + 192937984);        //  .. 209,715,200 (16 MB, V transposed)
  bf16* h1     = (bf16*)(ws);                    // 64 MB, reuses qkv_bf+x_bf (dead by FF)
  float* ff    = (float*)(ws + 109051904);       // 32 MB, reuses attn (dead after ln_res#1)

  // ---- input conversion / weight packing
  f32_to_bf16_k<<<8192, 256, 0, stream>>>(x, x_bf, (size_t)8388608);
  tr_to_bf16_k<<<dim3(2, 32, 16), 256, 0, stream>>>(Wq, WqkvT,               1024, 64,   65536, 65536);
  tr_to_bf16_k<<<dim3(2, 32, 16), 256, 0, stream>>>(Wk, WqkvT + 1024 * 1024, 1024, 64,   65536, 65536);
  tr_to_bf16_k<<<dim3(2, 32, 16), 256, 0, stream>>>(Wv, WqkvT + 2048 * 1024, 1024, 64,   65536, 65536);
  tr_to_bf16_k<<<dim3(32, 32, 1), 256, 0, stream>>>(Wo, WoT,                 1024, 1024, 0, 0);
  tr_to_bf16_k<<<dim3(128, 32, 1), 256, 0, stream>>>(W1, W1T,                1024, 4096, 0, 0);
  tr_to_bf16_k<<<dim3(32, 128, 1), 256, 0, stream>>>(W2, W2T,                4096, 1024, 0, 0);

  // ---- QKV projection (256x128 2-phase; 768 blocks = 3 exact rounds)
  gemmT<0, 128><<<dim3(24, 32), 512, 0, stream>>>(x_bf, WqkvT, nullptr, nullptr, qkv_bf, vt, 8192, 3072, 1024);

  // ---- MFMA flash attention (1024 balanced blocks, counted-vmcnt dbuf)
  attn_mfma<<<1024, 256, 0, stream>>>(qkv_bf, vt, o_bf);

  // ---- output projection + bias (256x128 2-phase, 256 blocks = 1 round)
  gemmT<1, 128><<<dim3(8, 32), 512, 0, stream>>>(o_bf, WoT, bo, attn, nullptr, nullptr, 8192, 1024, 1024);

  // ---- x1 = x + LN(attn)
  ln_res<<<8192, 256, 0, stream>>>(x, attn, x1, x1b);

  // ---- FF1 (256^2 4-phase, bias+relu; 512 blocks = 2 exact rounds --
  //      BN=128 doubled A-refetch and hit 96us, reverted per R12 data)
  gemmT<2, 256><<<dim3(16, 32), 512, 0, stream>>>(x1b, W1T, b1, nullptr, h1, nullptr, 8192, 4096, 1024);

  // ---- FF2 (256x128 2-phase)
  gemmT<1, 128><<<dim3(8, 32), 512, 0, stream>>>(h1, W2T, b2, ff, nullptr, nullptr, 8192, 1024, 4096);

  // ---- out = x1 + LN(ff)
  ln_res<<<8192, 256, 0, stream>>>(x1, ff, out, nullptr);
}